// Round 4
// baseline (405.562 us; speedup 1.0000x reference)
//
#include <hip/hip_runtime.h>
#include <cstdint>
#include <cstddef>

// ExpertGather: Y[b,e,k,j] = sum_i X[b, ind[b,e,k], i] * W[e,i,j]
// B=4 T=4096 I=1024 E=16 K=512 J=1024
// Round 4: back to m97-proven 128x128/BK64/256thr shape (4 blocks/CU, 2048
// blocks oversubscribed) — round 3's 256^2 tile was occupancy-starved (2/CU,
// MfmaUtil 25%). Keep: async16+XOR swizzle (0 conflicts, r2), full-line LDS
// epilogue (WRITE==output, r3), and add XCD-aware mapping (2 experts/XCD,
// B-tile sharers consecutive). Converts fused into one dispatch.

typedef float    floatx4 __attribute__((ext_vector_type(4)));
typedef _Float16 half8   __attribute__((ext_vector_type(8)));

constexpr int Bc = 4, Tc = 4096, Ic = 1024, Ec = 16, Kc = 512, Jc = 1024;
constexpr int BM = 128, BN = 128, BK = 64, NT = 256;

__device__ __forceinline__ void async16(const void* g, void* l) {
  __builtin_amdgcn_global_load_lds(
      (const __attribute__((address_space(1))) uint32_t*)g,
      (__attribute__((address_space(3))) uint32_t*)l, 16, 0, 0);
}

// ---------- fused pre-pass: X fp32->fp16 (blocks 0..2047), W -> W^T fp16 (rest) ----------
__global__ void cvt_kernel(const float* __restrict__ X, _Float16* __restrict__ Xh,
                           const float* __restrict__ W, _Float16* __restrict__ WT) {
  __shared__ float tile[64][65];
  const int tid = threadIdx.x;
  if (blockIdx.x < 2048) {
    // X convert: 2048 blocks x 256 thr x 4 iters of half8 = 16.78M halves exact
    int i = blockIdx.x * 256 + tid;
#pragma unroll
    for (int k = 0; k < 4; k++, i += 2048 * 256) {
      floatx4 v0 = ((const floatx4*)X)[2 * i];
      floatx4 v1 = ((const floatx4*)X)[2 * i + 1];
      half8 h;
      h[0] = (_Float16)v0.x; h[1] = (_Float16)v0.y; h[2] = (_Float16)v0.z; h[3] = (_Float16)v0.w;
      h[4] = (_Float16)v1.x; h[5] = (_Float16)v1.y; h[6] = (_Float16)v1.z; h[7] = (_Float16)v1.w;
      ((half8*)Xh)[i] = h;
    }
  } else {
    // W transpose+convert: 4096 blocks, 64x64 tiles
    const int bid = blockIdx.x - 2048;
    const int e  = bid >> 8;
    const int i0 = ((bid >> 4) & 15) * 64;
    const int j0 = (bid & 15) * 64;
    const int r  = tid >> 4;
    const int c4 = tid & 15;
    const float* src = W + ((size_t)e << 20) + (size_t)i0 * Jc + j0;
#pragma unroll
    for (int s = 0; s < 4; s++) {
      int rr = r + s * 16;
      floatx4 v = *(const floatx4*)(src + (size_t)rr * Jc + c4 * 4);
      tile[rr][c4 * 4 + 0] = v.x; tile[rr][c4 * 4 + 1] = v.y;
      tile[rr][c4 * 4 + 2] = v.z; tile[rr][c4 * 4 + 3] = v.w;
    }
    __syncthreads();
    const int jj = tid >> 2;
    const int ig = tid & 3;
    half8 hv0, hv1;
#pragma unroll
    for (int q = 0; q < 8; q++) hv0[q] = (_Float16)tile[ig * 16 + q][jj];
#pragma unroll
    for (int q = 0; q < 8; q++) hv1[q] = (_Float16)tile[ig * 16 + 8 + q][jj];
    _Float16* dst = WT + ((size_t)e << 20) + (size_t)(j0 + jj) * Ic + i0 + ig * 16;
    ((half8*)dst)[0] = hv0;
    ((half8*)dst)[1] = hv1;
  }
}

// ---------- main grouped GEMM ----------
// 2048 blocks. Mapping: xcd=bid&7 -> e=(xcd<<1)|(r&1): 2 experts per XCD (WT
// 4MB L2-resident); within expert, the 16 (b,mt) sharers of each B-tile are
// consecutive in r -> co-resident in time, B-tile stays L2-hot.
// LDS: row r, logical chunk c (8 halves) stored at chunk c^(r&7); swizzle
// applied on the per-lane GLOBAL address (global_load_lds fill is lane-ordered).
// MFMA layouts (m89-verified): A/B m(n)=lane&15, k=(lane>>4)*8+j;
// C/D col=lane&15, row=(lane>>4)*4+reg.
__global__ __launch_bounds__(NT, 4) void gemm_kernel(
    const int* __restrict__ ind32,
    const _Float16* __restrict__ Xh, const _Float16* __restrict__ WT,
    float* __restrict__ Y) {
  __shared__ alignas(16) _Float16 As[BM * BK];  // 16 KB
  __shared__ alignas(16) _Float16 Bs[BN * BK];  // 16 KB
  __shared__ int rowid[BM];
  __shared__ int is64_s;
  float* lbuf = (float*)As;  // epilogue reuse: 32 x 129 floats = 16.5 KB

  const int tid = threadIdx.x;
  const int bid = blockIdx.x;
  const int xcd = bid & 7;
  const int r   = bid >> 3;           // 0..255
  const int e   = (xcd << 1) | (r & 1);
  const int rr  = r >> 1;             // 0..127
  const int nt  = rr >> 4;            // 0..7
  const int b   = (rr >> 2) & 3;
  const int mt  = rr & 3;
  const int be  = b * Ec + e;
  const int k0  = mt * BM;
  const int j0  = nt * BN;

  // index dtype probe (int64 vs int32 storage)
  if (tid == 0) {
    int orv = 0;
    for (int q = 1; q < 256; q += 2) orv |= ind32[q];
    is64_s = (orv == 0) ? 1 : 0;
  }
  __syncthreads();
  if (tid < BM) {
    int idx = be * Kc + k0 + tid;
    rowid[tid] = is64_s ? ind32[2 * idx] : ind32[idx];
  }
  __syncthreads();

  const int lane = tid & 63;
  const int wave = tid >> 6;          // 0..3
  const int wm = (wave >> 1) * 64;
  const int wn = (wave & 1) * 64;
  const int quad = lane >> 4;
  const int tr = lane & 15;
  const int t7 = tr & 7;
  const int lr = lane >> 3;           // row within 8-row staging group
  const int cst = lane & 7;           // stored chunk position (lane-ordered)
  const int cdat = cst ^ lr;          // data chunk this lane fetches

  const _Float16* aptr[4];
  const _Float16* bptr[4];
#pragma unroll
  for (int q = 0; q < 4; q++) {
    const int rowA = (wave * 4 + q) * 8 + lr;  // 0..127
    aptr[q] = Xh + ((size_t)b * Tc + rowid[rowA]) * Ic + cdat * 8;
    bptr[q] = WT + ((size_t)e * Jc + j0 + rowA) * Ic + cdat * 8;
  }

  floatx4 acc[4][4];
#pragma unroll
  for (int mi = 0; mi < 4; mi++)
#pragma unroll
    for (int ni = 0; ni < 4; ni++) acc[mi][ni] = {0.f, 0.f, 0.f, 0.f};

  for (int kk = 0; kk < Ic; kk += BK) {
#pragma unroll
    for (int q = 0; q < 4; q++)
      async16(aptr[q] + kk, &As[(wave * 4 + q) * 512]);
#pragma unroll
    for (int q = 0; q < 4; q++)
      async16(bptr[q] + kk, &Bs[(wave * 4 + q) * 512]);
    __syncthreads();

#pragma unroll
    for (int ks = 0; ks < 2; ks++) {
      const int cofs = ((ks * 4 + quad) ^ t7) * 8;
      half8 af[4], bf[4];
#pragma unroll
      for (int mi = 0; mi < 4; mi++)
        af[mi] = *(const half8*)&As[(wm + mi * 16 + tr) * 64 + cofs];
#pragma unroll
      for (int ni = 0; ni < 4; ni++)
        bf[ni] = *(const half8*)&Bs[(wn + ni * 16 + tr) * 64 + cofs];
#pragma unroll
      for (int mi = 0; mi < 4; mi++)
#pragma unroll
        for (int ni = 0; ni < 4; ni++)
          acc[mi][ni] = __builtin_amdgcn_mfma_f32_16x16x32_f16(af[mi], bf[ni], acc[mi][ni], 0, 0, 0);
    }
    __syncthreads();
  }

  // ---- epilogue: 4 passes of 32 rows x 128 cols through LDS, full-line stores
  constexpr int LST = 129;
  float* Yb = Y + (size_t)be * Kc * Jc;
#pragma unroll
  for (int pass = 0; pass < 4; pass++) {
    if ((wave >> 1) == (pass >> 1)) {
#pragma unroll
      for (int h = 0; h < 2; h++) {
        const int mi = (pass & 1) * 2 + h;
        const int rloc = h * 16 + quad * 4;
#pragma unroll
        for (int ni = 0; ni < 4; ni++) {
          const int col = wn + ni * 16 + tr;
#pragma unroll
          for (int v = 0; v < 4; v++)
            lbuf[(rloc + v) * LST + col] = acc[mi][ni][v];
        }
      }
    }
    __syncthreads();
    // cooperative store: 32 rows x 32 float4 = 1024 float4 / 256 threads
#pragma unroll
    for (int it = 0; it < 4; it++) {
      const int idx = tid + it * NT;
      const int rw = idx >> 5, c4 = idx & 31;
      floatx4 v = *(const floatx4*)&lbuf[rw * LST + c4 * 4];
      *(floatx4*)&Yb[(size_t)(k0 + pass * 32 + rw) * Jc + j0 + c4 * 4] = v;
    }
    __syncthreads();
  }
}

extern "C" void kernel_launch(void* const* d_in, const int* in_sizes, int n_in,
                              void* d_out, int out_size, void* d_ws, size_t ws_size,
                              hipStream_t stream) {
  const float* X = (const float*)d_in[0];
  const int* ind = (const int*)d_in[1];
  const float* W = (const float*)d_in[2];
  float* Y = (float*)d_out;

  const size_t nx = (size_t)Bc * Tc * Ic;
  _Float16* Xh = (_Float16*)d_ws;
  _Float16* WT = Xh + nx;

  cvt_kernel<<<2048 + 4096, 256, 0, stream>>>(X, Xh, W, WT);
  const int gemm_grid = (Bc * Ec) * (Kc / BM) * (Jc / BN);  // 2048
  gemm_kernel<<<gemm_grid, NT, 0, stream>>>(ind, Xh, WT, Y);
}